// Round 1
// baseline (411.108 us; speedup 1.0000x reference)
//
#include <hip/hip_runtime.h>
#include <hip/hip_bf16.h>

#define HIDDEN 1024
#define NHEADS 16
#define HEADD  64
#define BATCH  8
#define SEQ    1024
#define MROWS  (BATCH*SEQ)   // 8192

typedef __bf16 bf16x8 __attribute__((ext_vector_type(8)));
typedef float  floatx4 __attribute__((ext_vector_type(4)));
typedef unsigned short ushort8_t __attribute__((ext_vector_type(8)));

__device__ __forceinline__ unsigned short f2bf(float f) {
  __hip_bfloat16 h = __float2bfloat16(f);
  return __builtin_bit_cast(unsigned short, h);
}

__device__ __forceinline__ bf16x8 ld_bf8(const unsigned short* p) {
  ushort8_t u = *(const ushort8_t*)p;
  return __builtin_bit_cast(bf16x8, u);
}

// ---------------------------------------------------------------- cast x -> bf16
__global__ __launch_bounds__(256) void cast_x_kernel(const float* __restrict__ in,
                                                     unsigned short* __restrict__ out) {
  int i = blockIdx.x * 256 + threadIdx.x;      // each thread: 4 floats
  float4 v = ((const float4*)in)[i];
  ushort4 o = make_ushort4(f2bf(v.x), f2bf(v.y), f2bf(v.z), f2bf(v.w));
  ((ushort4*)out)[i] = o;
}

// ------------------------------------------- transpose+cast weights: [K][N] f32 -> [N][K] bf16
__global__ __launch_bounds__(256) void transpose_cast_w_kernel(
    const float* __restrict__ w0, const float* __restrict__ w1,
    const float* __restrict__ w2, const float* __restrict__ w3,
    unsigned short* __restrict__ o0, unsigned short* __restrict__ o1,
    unsigned short* __restrict__ o2, unsigned short* __restrict__ o3) {
  __shared__ __align__(16) unsigned short tile[64 * 68];
  const float* src = (blockIdx.z == 0) ? w0 : (blockIdx.z == 1) ? w1 : (blockIdx.z == 2) ? w2 : w3;
  unsigned short* dst = (blockIdx.z == 0) ? o0 : (blockIdx.z == 1) ? o1 : (blockIdx.z == 2) ? o2 : o3;
  const int k0 = blockIdx.x * 64, n0 = blockIdx.y * 64;
  const int tid = threadIdx.x;
#pragma unroll
  for (int it = 0; it < 4; ++it) {
    int c = tid + 256 * it;
    int row = c >> 4, f4 = c & 15;
    float4 v = *(const float4*)(src + (size_t)(k0 + row) * HIDDEN + n0 + 4 * f4);
    ushort4 u = make_ushort4(f2bf(v.x), f2bf(v.y), f2bf(v.z), f2bf(v.w));
    *(ushort4*)(&tile[row * 68 + 4 * f4]) = u;
  }
  __syncthreads();
#pragma unroll
  for (int it = 0; it < 2; ++it) {
    int c = tid + 256 * it;
    int nrow = c >> 3, kc = (c & 7) * 8;
    ushort8_t u;
#pragma unroll
    for (int j = 0; j < 8; ++j) u[j] = tile[(kc + j) * 68 + nrow];
    *(ushort8_t*)(dst + (size_t)(n0 + nrow) * HIDDEN + k0 + kc) = u;
  }
}

// ---------------------------------------------------------------- bf16 GEMM: C = A[M][K] * Bt[N][K]^T
// M=8192, N=K=1024 fixed. 128x128 block tile, 4 waves (2x2), wave = 64x64 via 4x4 MFMA 16x16x32.
template <bool OUT_BF16>
__global__ __launch_bounds__(256) void gemm_bt_kernel(
    const unsigned short* __restrict__ A,
    const unsigned short* __restrict__ Bt,
    const float* __restrict__ bias,
    void* __restrict__ Cout,
    float scale) {
  constexpr int K = 1024, N = 1024;
  __shared__ __align__(16) unsigned short As[128 * 40];
  __shared__ __align__(16) unsigned short Bs[128 * 40];
  const int tid = threadIdx.x;
  const int lane = tid & 63;
  const int wave = tid >> 6;
  const int wm = wave >> 1, wn = wave & 1;
  const int m0 = blockIdx.y * 128;
  const int n0 = blockIdx.x * 128;
  const int lq = lane >> 4, lr = lane & 15;
  const int srow = tid >> 2;          // 0..63
  const int scol = (tid & 3) * 8;     // 0,8,16,24

  floatx4 acc[4][4] = {};

  for (int k0 = 0; k0 < K; k0 += 32) {
    __syncthreads();
    {
      const unsigned short* ga = A + (size_t)(m0 + srow) * K + k0 + scol;
      *(int4*)(&As[srow * 40 + scol]) = *(const int4*)ga;
      *(int4*)(&As[(srow + 64) * 40 + scol]) = *(const int4*)(ga + (size_t)64 * K);
      const unsigned short* gb = Bt + (size_t)(n0 + srow) * K + k0 + scol;
      *(int4*)(&Bs[srow * 40 + scol]) = *(const int4*)gb;
      *(int4*)(&Bs[(srow + 64) * 40 + scol]) = *(const int4*)(gb + (size_t)64 * K);
    }
    __syncthreads();
    bf16x8 af[4], bfr[4];
#pragma unroll
    for (int t = 0; t < 4; ++t) {
      af[t]  = ld_bf8(&As[(64 * wm + 16 * t + lr) * 40 + lq * 8]);
      bfr[t] = ld_bf8(&Bs[(64 * wn + 16 * t + lr) * 40 + lq * 8]);
    }
#pragma unroll
    for (int mt = 0; mt < 4; ++mt)
#pragma unroll
      for (int nt = 0; nt < 4; ++nt)
        acc[mt][nt] = __builtin_amdgcn_mfma_f32_16x16x32_bf16(af[mt], bfr[nt], acc[mt][nt], 0, 0, 0);
  }

  // epilogue: C[row][col] ; D-layout row=lq*4+r, col=lr
#pragma unroll
  for (int nt = 0; nt < 4; ++nt) {
    int col = n0 + 64 * wn + 16 * nt + lr;
    float bv_ = bias[col];
#pragma unroll
    for (int mt = 0; mt < 4; ++mt) {
      int row0 = m0 + 64 * wm + 16 * mt + lq * 4;
#pragma unroll
      for (int r = 0; r < 4; ++r) {
        float v = (acc[mt][nt][r] + bv_) * scale;
        if constexpr (OUT_BF16)
          ((unsigned short*)Cout)[(size_t)(row0 + r) * N + col] = f2bf(v);
        else
          ((float*)Cout)[(size_t)(row0 + r) * N + col] = v;
      }
    }
  }
}

// ---------------------------------------------------------------- flash attention
// Q pre-scaled by 1/32. One block = (b, h, 64 q-rows). 4 waves, each 16 q-rows.
__global__ __launch_bounds__(256) void attn_kernel(
    const unsigned short* __restrict__ Qb,
    const unsigned short* __restrict__ Kb,
    const unsigned short* __restrict__ Vb,
    unsigned short* __restrict__ Og) {
  __shared__ __align__(16) unsigned short Qs[64 * 72];
  __shared__ __align__(16) unsigned short Ks[64 * 72];
  __shared__ __align__(16) unsigned short Vt[64 * 72];   // transposed: Vt[d][key]
  __shared__ __align__(16) unsigned short Ps[4 * 16 * 72];

  const int tid = threadIdx.x;
  const int lane = tid & 63;
  const int wave = tid >> 6;
  const int lq = lane >> 4, lr = lane & 15;
  const int q0 = blockIdx.x * 64;
  const int h = blockIdx.y, b = blockIdx.z;
  const size_t base = ((size_t)b * SEQ) * HIDDEN + h * HEADD;

  const int srow = tid >> 3;        // 0..31
  const int scol = (tid & 7) * 8;   // 0..56

  {
    const unsigned short* gq = Qb + base + (size_t)(q0 + srow) * HIDDEN + scol;
    *(int4*)(&Qs[srow * 72 + scol]) = *(const int4*)gq;
    *(int4*)(&Qs[(srow + 32) * 72 + scol]) = *(const int4*)(gq + (size_t)32 * HIDDEN);
  }

  float m_i[4], l_i[4], alpha[4];
  floatx4 oacc[4] = {};
#pragma unroll
  for (int r = 0; r < 4; ++r) { m_i[r] = -1e30f; l_i[r] = 0.f; }

  unsigned short* Pw = &Ps[wave * 16 * 72];
  constexpr float L2E = 1.44269504088896f;

  for (int kt = 0; kt < SEQ / 64; ++kt) {
    __syncthreads();
    {
      const unsigned short* gk = Kb + base + (size_t)(kt * 64 + srow) * HIDDEN + scol;
      *(int4*)(&Ks[srow * 72 + scol]) = *(const int4*)gk;
      *(int4*)(&Ks[(srow + 32) * 72 + scol]) = *(const int4*)(gk + (size_t)32 * HIDDEN);
      const unsigned short* gv = Vb + base + (size_t)(kt * 64 + srow) * HIDDEN + scol;
      ushort8_t rv0 = *(const ushort8_t*)gv;
      ushort8_t rv1 = *(const ushort8_t*)(gv + (size_t)32 * HIDDEN);
#pragma unroll
      for (int j = 0; j < 8; ++j) {
        Vt[(scol + j) * 72 + srow] = rv0[j];
        Vt[(scol + j) * 72 + srow + 32] = rv1[j];
      }
    }
    __syncthreads();

    // S = Q * K^T  (contraction over d=64 in 2 MFMA steps)
    floatx4 s[4] = {};
#pragma unroll
    for (int st = 0; st < 2; ++st) {
      bf16x8 aq = ld_bf8(&Qs[(16 * wave + lr) * 72 + st * 32 + lq * 8]);
#pragma unroll
      for (int nt = 0; nt < 4; ++nt) {
        bf16x8 bk = ld_bf8(&Ks[(16 * nt + lr) * 72 + st * 32 + lq * 8]);
        s[nt] = __builtin_amdgcn_mfma_f32_16x16x32_bf16(aq, bk, s[nt], 0, 0, 0);
      }
    }

    // online softmax: each lane owns rows lq*4+r, cols nt*16+lr
#pragma unroll
    for (int r = 0; r < 4; ++r) {
      float mx = fmaxf(fmaxf(s[0][r], s[1][r]), fmaxf(s[2][r], s[3][r]));
#pragma unroll
      for (int off = 1; off < 16; off <<= 1) mx = fmaxf(mx, __shfl_xor(mx, off));
      float mnew = fmaxf(m_i[r], mx);
      alpha[r] = exp2f((m_i[r] - mnew) * L2E);
      float sum = 0.f;
#pragma unroll
      for (int nt = 0; nt < 4; ++nt) {
        float p = exp2f((s[nt][r] - mnew) * L2E);
        s[nt][r] = p;
        sum += p;
      }
#pragma unroll
      for (int off = 1; off < 16; off <<= 1) sum += __shfl_xor(sum, off);
      l_i[r] = l_i[r] * alpha[r] + sum;
      m_i[r] = mnew;
    }

    // P: C-layout -> LDS -> A-layout (per-wave private region)
#pragma unroll
    for (int nt = 0; nt < 4; ++nt)
#pragma unroll
      for (int r = 0; r < 4; ++r)
        Pw[(lq * 4 + r) * 72 + nt * 16 + lr] = f2bf(s[nt][r]);

#pragma unroll
    for (int t = 0; t < 4; ++t)
#pragma unroll
      for (int r = 0; r < 4; ++r) oacc[t][r] *= alpha[r];

    // O += P * V  (contraction over key=64 in 2 MFMA steps)
#pragma unroll
    for (int st = 0; st < 2; ++st) {
      bf16x8 ap = ld_bf8(&Pw[lr * 72 + st * 32 + lq * 8]);
#pragma unroll
      for (int t = 0; t < 4; ++t) {
        bf16x8 bv2 = ld_bf8(&Vt[(16 * t + lr) * 72 + st * 32 + lq * 8]);
        oacc[t] = __builtin_amdgcn_mfma_f32_16x16x32_bf16(ap, bv2, oacc[t], 0, 0, 0);
      }
    }
  }

#pragma unroll
  for (int r = 0; r < 4; ++r) {
    float inv = 1.0f / l_i[r];
    int qrow = q0 + 16 * wave + lq * 4 + r;
#pragma unroll
    for (int t = 0; t < 4; ++t)
      Og[base + (size_t)qrow * HIDDEN + 16 * t + lr] = f2bf(oacc[t][r] * inv);
  }
}

// ----------------------------------------------------------------
extern "C" void kernel_launch(void* const* d_in, const int* in_sizes, int n_in,
                              void* d_out, int out_size, void* d_ws, size_t ws_size,
                              hipStream_t stream) {
  const float* x  = (const float*)d_in[0];
  const float* wq = (const float*)d_in[1];
  const float* bq = (const float*)d_in[2];
  const float* wk = (const float*)d_in[3];
  const float* bk = (const float*)d_in[4];
  const float* wv = (const float*)d_in[5];
  const float* bv = (const float*)d_in[6];
  const float* wo = (const float*)d_in[7];
  const float* bo = (const float*)d_in[8];

  char* ws = (char*)d_ws;
  const size_t XB = (size_t)MROWS * HIDDEN * 2;   // 16 MiB
  const size_t WB = (size_t)HIDDEN * HIDDEN * 2;  // 2 MiB
  unsigned short* xb  = (unsigned short*)(ws);
  unsigned short* wqt = (unsigned short*)(ws + XB);
  unsigned short* wkt = (unsigned short*)(ws + XB + WB);
  unsigned short* wvt = (unsigned short*)(ws + XB + 2 * WB);
  unsigned short* wot = (unsigned short*)(ws + XB + 3 * WB);
  unsigned short* Qb  = (unsigned short*)(ws + XB + 4 * WB);
  unsigned short* Kb  = (unsigned short*)(ws + 2 * XB + 4 * WB);
  unsigned short* Vb  = (unsigned short*)(ws + 3 * XB + 4 * WB);
  unsigned short* Mg  = (unsigned short*)(ws + 4 * XB + 4 * WB);

  // 1. casts
  cast_x_kernel<<<(MROWS * HIDDEN / 4) / 256, 256, 0, stream>>>(x, xb);
  transpose_cast_w_kernel<<<dim3(16, 16, 4), 256, 0, stream>>>(wq, wk, wv, wo, wqt, wkt, wvt, wot);

  // 2. QKV projections (Q scaled by 1/sqrt(HIDDEN)=1/32, exact in bf16)
  dim3 gg(HIDDEN / 128, MROWS / 128);
  gemm_bt_kernel<true><<<gg, 256, 0, stream>>>(xb, wqt, bq, Qb, 1.0f / 32.0f);
  gemm_bt_kernel<true><<<gg, 256, 0, stream>>>(xb, wkt, bk, Kb, 1.0f);
  gemm_bt_kernel<true><<<gg, 256, 0, stream>>>(xb, wvt, bv, Vb, 1.0f);

  // 3. attention
  attn_kernel<<<dim3(SEQ / 64, NHEADS, BATCH), 256, 0, stream>>>(Qb, Kb, Vb, Mg);

  // 4. output projection -> fp32 d_out
  gemm_bt_kernel<false><<<gg, 256, 0, stream>>>(Mg, wot, bo, (float*)d_out, 1.0f);
}

// Round 2
// 307.677 us; speedup vs baseline: 1.3362x; 1.3362x over previous
//
#include <hip/hip_runtime.h>
#include <hip/hip_bf16.h>

#define HIDDEN 1024
#define NHEADS 16
#define HEADD  64
#define BATCH  8
#define SEQ    1024
#define MROWS  (BATCH*SEQ)   // 8192

typedef __bf16 bf16x8 __attribute__((ext_vector_type(8)));
typedef float  floatx4 __attribute__((ext_vector_type(4)));
typedef unsigned short ushort8_t __attribute__((ext_vector_type(8)));
typedef const __attribute__((address_space(1))) unsigned int* gas_u32p;
typedef __attribute__((address_space(3))) unsigned int* las_u32p;

__device__ __forceinline__ unsigned short f2bf(float f) {
  __hip_bfloat16 h = __float2bfloat16(f);
  return __builtin_bit_cast(unsigned short, h);
}

__device__ __forceinline__ bf16x8 ld_bf8(const unsigned short* p) {
  ushort8_t u = *(const ushort8_t*)p;
  return __builtin_bit_cast(bf16x8, u);
}

__device__ __forceinline__ void gload_lds16(const unsigned short* g, unsigned short* l) {
  __builtin_amdgcn_global_load_lds((gas_u32p)(const void*)g, (las_u32p)(void*)l, 16, 0, 0);
}

// ---------------------------------------------------------------- cast x -> bf16
__global__ __launch_bounds__(256) void cast_x_kernel(const float* __restrict__ in,
                                                     unsigned short* __restrict__ out) {
  int i = blockIdx.x * 256 + threadIdx.x;      // each thread: 4 floats
  float4 v = ((const float4*)in)[i];
  ushort4 o = make_ushort4(f2bf(v.x), f2bf(v.y), f2bf(v.z), f2bf(v.w));
  ((ushort4*)out)[i] = o;
}

// ------------------------------------------- transpose+cast weights: [K][N] f32 -> [N][K] bf16
__global__ __launch_bounds__(256) void transpose_cast_w_kernel(
    const float* __restrict__ w0, const float* __restrict__ w1,
    const float* __restrict__ w2, const float* __restrict__ w3,
    unsigned short* __restrict__ o0, unsigned short* __restrict__ o1,
    unsigned short* __restrict__ o2, unsigned short* __restrict__ o3) {
  __shared__ __align__(16) unsigned short tile[64 * 68];
  const float* src = (blockIdx.z == 0) ? w0 : (blockIdx.z == 1) ? w1 : (blockIdx.z == 2) ? w2 : w3;
  unsigned short* dst = (blockIdx.z == 0) ? o0 : (blockIdx.z == 1) ? o1 : (blockIdx.z == 2) ? o2 : o3;
  const int k0 = blockIdx.x * 64, n0 = blockIdx.y * 64;
  const int tid = threadIdx.x;
#pragma unroll
  for (int it = 0; it < 4; ++it) {
    int c = tid + 256 * it;
    int row = c >> 4, f4 = c & 15;
    float4 v = *(const float4*)(src + (size_t)(k0 + row) * HIDDEN + n0 + 4 * f4);
    ushort4 u = make_ushort4(f2bf(v.x), f2bf(v.y), f2bf(v.z), f2bf(v.w));
    *(ushort4*)(&tile[row * 68 + 4 * f4]) = u;
  }
  __syncthreads();
#pragma unroll
  for (int it = 0; it < 2; ++it) {
    int c = tid + 256 * it;
    int nrow = c >> 3, kc = (c & 7) * 8;
    ushort8_t u;
#pragma unroll
    for (int j = 0; j < 8; ++j) u[j] = tile[(kc + j) * 68 + nrow];
    *(ushort8_t*)(dst + (size_t)(n0 + nrow) * HIDDEN + k0 + kc) = u;
  }
}

// ---------------------------------------------------------------- bf16 GEMM (m97 structure)
// C[m][n] = sum_k A[m][k]*Bt[n][k] (+bias)*scale. K=1024. 128x128 tile, BK=32,
// unpadded LDS + global_load_lds width 16.
template <int BIAS_ROW, bool OUT_BF16>
__global__ __launch_bounds__(256) void gemm_lds_kernel(
    const unsigned short* __restrict__ A,   // [M][1024]
    const unsigned short* __restrict__ Bt,  // [N][1024]
    const float* __restrict__ bias,
    void* __restrict__ Cout, int Nout, float scale) {
  constexpr int K = 1024;
  __shared__ __align__(16) unsigned short As[128 * 32];
  __shared__ __align__(16) unsigned short Bs[128 * 32];
  const int tid = threadIdx.x;
  const int lane = tid & 63;
  const int wv = tid >> 6;
  const int wm = wv >> 1, wn = wv & 1;
  const int m0 = blockIdx.y * 128;
  const int n0 = blockIdx.x * 128;
  const int lq = lane >> 4, lr = lane & 15;
  // staging: wave wv covers rows [32wv,32wv+32) of A and B, 2 instrs each
  const int srow = lane >> 2;        // 0..15 within instr
  const int scol = (lane & 3) * 8;   // shorts

  const unsigned short* ga = A  + (size_t)(m0 + wv * 32 + srow) * K + scol;
  const unsigned short* gb = Bt + (size_t)(n0 + wv * 32 + srow) * K + scol;
  unsigned short* lA = &As[(wv * 32) * 32];
  unsigned short* lB = &Bs[(wv * 32) * 32];

  floatx4 acc[4][4] = {};

  for (int k0 = 0; k0 < K; k0 += 32) {
    __syncthreads();
    gload_lds16(ga + k0,            lA);
    gload_lds16(ga + 16 * K + k0,   lA + 16 * 32);
    gload_lds16(gb + k0,            lB);
    gload_lds16(gb + 16 * K + k0,   lB + 16 * 32);
    __syncthreads();

    bf16x8 af[4], bfr[4];
#pragma unroll
    for (int t = 0; t < 4; ++t) {
      af[t]  = ld_bf8(&As[(64 * wm + 16 * t + lr) * 32 + lq * 8]);
      bfr[t] = ld_bf8(&Bs[(64 * wn + 16 * t + lr) * 32 + lq * 8]);
    }
#pragma unroll
    for (int mt = 0; mt < 4; ++mt)
#pragma unroll
      for (int nt = 0; nt < 4; ++nt)
        acc[mt][nt] = __builtin_amdgcn_mfma_f32_16x16x32_bf16(af[mt], bfr[nt], acc[mt][nt], 0, 0, 0);
  }

#pragma unroll
  for (int nt = 0; nt < 4; ++nt) {
    int col = n0 + 64 * wn + 16 * nt + lr;
#pragma unroll
    for (int mt = 0; mt < 4; ++mt) {
      int row0 = m0 + 64 * wm + 16 * mt + lq * 4;
#pragma unroll
      for (int r = 0; r < 4; ++r) {
        float bv_ = BIAS_ROW ? bias[row0 + r] : bias[col];
        float v = (acc[mt][nt][r] + bv_) * scale;
        if constexpr (OUT_BF16)
          ((unsigned short*)Cout)[(size_t)(row0 + r) * Nout + col] = f2bf(v);
        else
          ((float*)Cout)[(size_t)(row0 + r) * Nout + col] = v;
      }
    }
  }
}

// ---------------------------------------------------------------- flash attention (S^T form)
// Q pre-scaled by log2(e)/32 -> softmax in exp2 domain.
// Block = (b, h, 64 q). 4 waves, each 16 q. K-tile = 64. V comes in transposed [1024][8192].
__global__ __launch_bounds__(256) void attn_kernel(
    const unsigned short* __restrict__ Qb,   // [8192][1024]
    const unsigned short* __restrict__ Kb,   // [8192][1024]
    const unsigned short* __restrict__ Vtb,  // [1024][8192]
    unsigned short* __restrict__ Og) {       // [8192][1024]
  __shared__ __align__(16) unsigned short Qs[64 * 72];
  __shared__ __align__(16) unsigned short Ks[64 * 72];
  __shared__ __align__(16) unsigned short Vts[64 * 72];
  __shared__ __align__(16) unsigned short Ps[4 * 16 * 72];

  const int tid = threadIdx.x;
  const int lane = tid & 63;
  const int wv = tid >> 6;
  const int l = lane & 15;       // n-index inside 16-tiles
  const int Q8 = lane >> 4;      // quad
  const int q0 = blockIdx.x * 64;
  const int h = blockIdx.y, b = blockIdx.z;
  const size_t base = ((size_t)b * SEQ) * HIDDEN + h * HEADD;
  const int srow = tid >> 3;         // 0..31
  const int scol = (tid & 7) * 8;    // 0..56

  {
    const unsigned short* gq = Qb + base + (size_t)(q0 + srow) * HIDDEN + scol;
    *(int4*)(&Qs[srow * 72 + scol]) = *(const int4*)gq;
    *(int4*)(&Qs[(srow + 32) * 72 + scol]) = *(const int4*)(gq + (size_t)32 * HIDDEN);
  }

  float m_i = -1e30f, l_i = 0.f;   // state for q = q0 + 16*wv + l (replicated across quads)
  floatx4 oacc[4] = {};            // O[q=4*Q8+r][d=16*dt+l]
  unsigned short* Pw = &Ps[wv * 16 * 72];

  for (int kt = 0; kt < SEQ / 64; ++kt) {
    __syncthreads();
    {
      const unsigned short* gk = Kb + base + (size_t)(kt * 64 + srow) * HIDDEN + scol;
      *(int4*)(&Ks[srow * 72 + scol]) = *(const int4*)gk;
      *(int4*)(&Ks[(srow + 32) * 72 + scol]) = *(const int4*)(gk + (size_t)32 * HIDDEN);
      const unsigned short* gv = Vtb + (size_t)(h * 64 + srow) * MROWS + (size_t)b * SEQ + kt * 64 + scol;
      *(int4*)(&Vts[srow * 72 + scol]) = *(const int4*)gv;
      *(int4*)(&Vts[(srow + 32) * 72 + scol]) = *(const int4*)(gv + (size_t)32 * MROWS);
    }
    __syncthreads();

    // S^T[key][q] = K . Q^T : a = K chunk rows (m=key), b = Q rows (n=q)
    floatx4 sT[4] = {};
#pragma unroll
    for (int st = 0; st < 2; ++st) {
      bf16x8 bq = ld_bf8(&Qs[(16 * wv + l) * 72 + st * 32 + Q8 * 8]);
#pragma unroll
      for (int c = 0; c < 4; ++c) {
        bf16x8 aK = ld_bf8(&Ks[(16 * c + l) * 72 + st * 32 + Q8 * 8]);
        sT[c] = __builtin_amdgcn_mfma_f32_16x16x32_bf16(aK, bq, sT[c], 0, 0, 0);
      }
    }
    // lane holds keys {16c + 4*Q8 + r} for q = 16*wv + l (log2-domain scores)

    float mx = sT[0][0];
#pragma unroll
    for (int c = 0; c < 4; ++c)
#pragma unroll
      for (int r = 0; r < 4; ++r) mx = fmaxf(mx, sT[c][r]);
    mx = fmaxf(mx, __shfl_xor(mx, 16));
    mx = fmaxf(mx, __shfl_xor(mx, 32));
    float mnew = fmaxf(m_i, mx);
    float alpha = __builtin_amdgcn_exp2f(m_i - mnew);
    float sum = 0.f;
#pragma unroll
    for (int c = 0; c < 4; ++c)
#pragma unroll
      for (int r = 0; r < 4; ++r) {
        float p = __builtin_amdgcn_exp2f(sT[c][r] - mnew);
        sT[c][r] = p;
        sum += p;
      }
    sum += __shfl_xor(sum, 16);
    sum += __shfl_xor(sum, 32);
    l_i = l_i * alpha + sum;
    m_i = mnew;

    // write P[q=l][key] into per-wave LDS (packed pairs, ~free conflicts)
#pragma unroll
    for (int c = 0; c < 4; ++c) {
      unsigned int p01 = ((unsigned int)f2bf(sT[c][1]) << 16) | (unsigned int)f2bf(sT[c][0]);
      unsigned int p23 = ((unsigned int)f2bf(sT[c][3]) << 16) | (unsigned int)f2bf(sT[c][2]);
      *(unsigned int*)(&Pw[l * 72 + 16 * c + 4 * Q8])     = p01;
      *(unsigned int*)(&Pw[l * 72 + 16 * c + 4 * Q8 + 2]) = p23;
    }

    // rescale O rows by alpha(q = 4*Q8 + r)
    float a0 = __shfl(alpha, 4 * Q8 + 0);
    float a1 = __shfl(alpha, 4 * Q8 + 1);
    float a2 = __shfl(alpha, 4 * Q8 + 2);
    float a3 = __shfl(alpha, 4 * Q8 + 3);
#pragma unroll
    for (int dt = 0; dt < 4; ++dt) {
      oacc[dt][0] *= a0; oacc[dt][1] *= a1; oacc[dt][2] *= a2; oacc[dt][3] *= a3;
    }

    // O += P.V : a = P[q=l][key], b = Vt[d=16dt+l][key]
#pragma unroll
    for (int st = 0; st < 2; ++st) {
      bf16x8 aP = ld_bf8(&Pw[l * 72 + st * 32 + Q8 * 8]);
#pragma unroll
      for (int dt = 0; dt < 4; ++dt) {
        bf16x8 bV = ld_bf8(&Vts[(16 * dt + l) * 72 + st * 32 + Q8 * 8]);
        oacc[dt] = __builtin_amdgcn_mfma_f32_16x16x32_bf16(aP, bV, oacc[dt], 0, 0, 0);
      }
    }
  }

  float inv = 1.0f / l_i;
  float i0 = __shfl(inv, 4 * Q8 + 0);
  float i1 = __shfl(inv, 4 * Q8 + 1);
  float i2 = __shfl(inv, 4 * Q8 + 2);
  float i3 = __shfl(inv, 4 * Q8 + 3);
#pragma unroll
  for (int dt = 0; dt < 4; ++dt) {
    int col = 16 * dt + l;
    size_t rowb = base + (size_t)(q0 + 16 * wv + 4 * Q8) * HIDDEN + col;
    Og[rowb]              = f2bf(oacc[dt][0] * i0);
    Og[rowb + HIDDEN]     = f2bf(oacc[dt][1] * i1);
    Og[rowb + 2 * HIDDEN] = f2bf(oacc[dt][2] * i2);
    Og[rowb + 3 * HIDDEN] = f2bf(oacc[dt][3] * i3);
  }
}

// ----------------------------------------------------------------
extern "C" void kernel_launch(void* const* d_in, const int* in_sizes, int n_in,
                              void* d_out, int out_size, void* d_ws, size_t ws_size,
                              hipStream_t stream) {
  const float* x  = (const float*)d_in[0];
  const float* wq = (const float*)d_in[1];
  const float* bq = (const float*)d_in[2];
  const float* wk = (const float*)d_in[3];
  const float* bk = (const float*)d_in[4];
  const float* wv = (const float*)d_in[5];
  const float* bv = (const float*)d_in[6];
  const float* wo = (const float*)d_in[7];
  const float* bo = (const float*)d_in[8];

  char* ws = (char*)d_ws;
  const size_t XB = (size_t)MROWS * HIDDEN * 2;   // 16 MiB
  const size_t WB = (size_t)HIDDEN * HIDDEN * 2;  // 2 MiB
  unsigned short* xb  = (unsigned short*)(ws);
  unsigned short* wqt = (unsigned short*)(ws + XB);
  unsigned short* wkt = (unsigned short*)(ws + XB + WB);
  unsigned short* wvt = (unsigned short*)(ws + XB + 2 * WB);
  unsigned short* wot = (unsigned short*)(ws + XB + 3 * WB);
  unsigned short* Qb  = (unsigned short*)(ws + XB + 4 * WB);
  unsigned short* Kb  = (unsigned short*)(ws + 2 * XB + 4 * WB);
  unsigned short* Vtb = (unsigned short*)(ws + 3 * XB + 4 * WB);
  unsigned short* Mg  = (unsigned short*)(ws + 4 * XB + 4 * WB);

  // 1. casts
  cast_x_kernel<<<(MROWS * HIDDEN / 4) / 256, 256, 0, stream>>>(x, xb);
  transpose_cast_w_kernel<<<dim3(16, 16, 4), 256, 0, stream>>>(wq, wk, wv, wo, wqt, wkt, wvt, wot);

  // 2. projections. Q folded with 1/sqrt(1024) * log2(e) for exp2-domain softmax.
  const float SQSCALE = 1.44269504088896f / 32.0f;
  dim3 gQK(HIDDEN / 128, MROWS / 128);
  gemm_lds_kernel<0, true><<<gQK, 256, 0, stream>>>(xb, wqt, bq, Qb, HIDDEN, SQSCALE);
  gemm_lds_kernel<0, true><<<gQK, 256, 0, stream>>>(xb, wkt, bk, Kb, HIDDEN, 1.0f);
  // V^T = (Wv^T) x^T : A = wvt [1024][1024], B = xb [8192][1024] -> [1024][8192], bias per row
  gemm_lds_kernel<1, true><<<dim3(MROWS / 128, HIDDEN / 128), 256, 0, stream>>>(
      wvt, xb, bv, Vtb, MROWS, 1.0f);

  // 3. attention
  attn_kernel<<<dim3(SEQ / 64, NHEADS, BATCH), 256, 0, stream>>>(Qb, Kb, Vtb, Mg);

  // 4. output projection -> fp32 d_out
  gemm_lds_kernel<0, false><<<gQK, 256, 0, stream>>>(Mg, wot, bo, d_out, HIDDEN, 1.0f);
}